// Round 2
// baseline (454.714 us; speedup 1.0000x reference)
//
#include <hip/hip_runtime.h>
#include <math.h>

// Problem constants (from reference)
#define NCH 129
#define BS 8
#define TLEN 64000
#define LFRM 256          // frame stride == chunk length
#define NFRM 250          // number of frames / chunks
#define NSEQ (NCH * BS)   // 1032 sequences
#define NBK (BS * NFRM)   // 2000 (b,k) tiles
#define CLEAN_BLOCKS ((NBK + 63) / 64)   // 32 cleanup blocks (channel-128 outputs)

// Warm-up: first WARM_IIR steps of the previous chunk evolve the IIR state
// only; sigmoid+beta accumulate over the last LFRM-WARM_IIR steps.
// beta^128 = e^-16 -> truncation err ~1e-6, amplified <=128x by alpha-sum -> ~1e-4.
#define WARM_IIR 128

struct Coef { float b0, b1, b2, b3, b4, a1, a2, a3, a4; };

__device__ __forceinline__ Coef load_coef(const float* __restrict__ B,
                                          const float* __restrict__ A, int c) {
    Coef q;
    q.b0 = B[c * 5 + 0]; q.b1 = B[c * 5 + 1]; q.b2 = B[c * 5 + 2];
    q.b3 = B[c * 5 + 3]; q.b4 = B[c * 5 + 4];
    q.a1 = A[c * 5 + 1]; q.a2 = A[c * 5 + 2];
    q.a3 = A[c * 5 + 3]; q.a4 = A[c * 5 + 4];
    return q;
}

// Direct-form II transposed, order 4.
__device__ __forceinline__ float iir_step(const Coef& q, float x,
                                          float& z0, float& z1, float& z2, float& z3) {
    float y = fmaf(q.b0, x, z0);
    z0 = fmaf(-q.a1, y, fmaf(q.b1, x, z1));
    z1 = fmaf(-q.a2, y, fmaf(q.b2, x, z2));
    z2 = fmaf(-q.a3, y, fmaf(q.b3, x, z3));
    z3 = fmaf(-q.a4, y, q.b4 * x);
    return y;
}

// rcp-based sigmoid: ~4 VALU ops instead of the IEEE divide sequence.
__device__ __forceinline__ float sigmoidf(float x) {
    return __builtin_amdgcn_rcpf(1.0f + __expf(-x));
}

// ---------------------------------------------------------------------------
// Kernel A: per (c, b, chunk) zero-state order-4 IIR over the chunk -> final
// 4-state (forced response). zs layout: float4 at [k * NSEQ + (c*BS+b)].
// ---------------------------------------------------------------------------
__global__ __launch_bounds__(192) void kA_forced_state(
        const float* __restrict__ wav, const float* __restrict__ B,
        const float* __restrict__ A, float* __restrict__ zs) {
    __shared__ float xs[LFRM];
    int blk = blockIdx.x;            // b * NFRM + k
    int b = blk / NFRM;
    int k = blk - b * NFRM;
    const float* xg = wav + (size_t)b * TLEN + (size_t)k * LFRM;
    for (int i = threadIdx.x; i < LFRM; i += 192) xs[i] = xg[i];
    __syncthreads();
    int c = threadIdx.x;
    if (c >= NCH) return;
    Coef q = load_coef(B, A, c);
    float z0 = 0.f, z1 = 0.f, z2 = 0.f, z3 = 0.f;
    #pragma unroll 8
    for (int j = 0; j < LFRM; ++j) {
        (void)iir_step(q, xs[j], z0, z1, z2, z3);
    }
    ((float4*)zs)[(size_t)k * NSEQ + (c * BS + b)] = make_float4(z0, z1, z2, z3);
}

// ---------------------------------------------------------------------------
// Kernel B: per (c,b) sequence — M^256 by repeated squaring, then scan:
//   z_in[k] = M^L * z_in[k-1] + d[k-1],  z_in[0] = 0  (in place, k-major ->
// coalesced float4 loads across the 1032 lanes).
// ---------------------------------------------------------------------------
__global__ __launch_bounds__(64) void kB_state_scan(
        const float* __restrict__ A, float* __restrict__ zs) {
    int id = blockIdx.x * 64 + threadIdx.x;   // c * BS + b
    if (id >= NSEQ) return;
    int c = id / BS;
    float a1 = A[c * 5 + 1], a2 = A[c * 5 + 2], a3 = A[c * 5 + 3], a4 = A[c * 5 + 4];
    float M[4][4] = {{-a1, 1.f, 0.f, 0.f},
                     {-a2, 0.f, 1.f, 0.f},
                     {-a3, 0.f, 0.f, 1.f},
                     {-a4, 0.f, 0.f, 0.f}};
    for (int s = 0; s < 8; ++s) {        // M^(2^8) = M^256
        float R[4][4];
        for (int i = 0; i < 4; ++i)
            for (int j = 0; j < 4; ++j) {
                float acc = 0.f;
                for (int t = 0; t < 4; ++t) acc = fmaf(M[i][t], M[t][j], acc);
                R[i][j] = acc;
            }
        for (int i = 0; i < 4; ++i)
            for (int j = 0; j < 4; ++j) M[i][j] = R[i][j];
    }
    float4* zb = (float4*)zs;
    float s0 = 0.f, s1 = 0.f, s2 = 0.f, s3 = 0.f;
    for (int k = 0; k < NFRM; k += 5) {            // 250 = 5*50
        float4 d[5];
        #pragma unroll
        for (int u = 0; u < 5; ++u) d[u] = zb[(size_t)(k + u) * NSEQ + id];
        #pragma unroll
        for (int u = 0; u < 5; ++u) {
            zb[(size_t)(k + u) * NSEQ + id] = make_float4(s0, s1, s2, s3);
            float n0 = fmaf(M[0][0], s0, fmaf(M[0][1], s1, fmaf(M[0][2], s2, fmaf(M[0][3], s3, d[u].x))));
            float n1 = fmaf(M[1][0], s0, fmaf(M[1][1], s1, fmaf(M[1][2], s2, fmaf(M[1][3], s3, d[u].y))));
            float n2 = fmaf(M[2][0], s0, fmaf(M[2][1], s1, fmaf(M[2][2], s2, fmaf(M[2][3], s3, d[u].z))));
            float n3 = fmaf(M[3][0], s0, fmaf(M[3][1], s1, fmaf(M[3][2], s2, fmaf(M[3][3], s3, d[u].w))));
            s0 = n0; s1 = n1; s2 = n2; s3 = n3;
        }
    }
}

// ---------------------------------------------------------------------------
// Kernel C: pair-channel main pass.
// Blocks [0, CLEAN_BLOCKS): cleanup — one thread per (b,k), chains 127 & 128,
//   emits channel-128 output terms (scheduled first so they hide under main).
// Blocks [CLEAN_BLOCKS, CLEAN_BLOCKS+NBK): main — one wave per (b,k); lane t
//   computes chains 2t & 2t+1 from exact z_in[k-1], warm-up over chunk k-1,
//   then emits y4-terms for channels 2t+1 (local) and 2t+2 (shfl_down).
// G/y4f layout: [(b*NFRM+k)*NCH + c] (c-major -> coalesced kD reads).
// ---------------------------------------------------------------------------
__global__ __launch_bounds__(64) void kC_main(
        const float* __restrict__ wav, const float* __restrict__ B,
        const float* __restrict__ A, const float* __restrict__ zs,
        float* __restrict__ G, float* __restrict__ y4f,
        float beta, float alpha) {
    __shared__ float xs[2 * LFRM];
    int blk = blockIdx.x;

    if (blk < CLEAN_BLOCKS) {
        // ---- cleanup: channel 128 ----
        int item = blk * 64 + threadIdx.x;   // b * NFRM + k
        if (item >= NBK) return;
        int b = item / NFRM;
        int k = item - b * NFRM;
        int kload = (k > 0) ? (k - 1) : 0;
        const float* xg = wav + (size_t)b * TLEN + (size_t)kload * LFRM;
        Coef qa = load_coef(B, A, 128);      // uniform across lanes
        Coef qb = load_coef(B, A, 127);
        float za0 = 0.f, za1 = 0.f, za2 = 0.f, za3 = 0.f;
        float zb0 = 0.f, zb1 = 0.f, zb2 = 0.f, zb3 = 0.f;
        float ua = 0.f, ub = 0.f;
        int off = 0;
        if (k > 0) {
            float4 va = ((const float4*)zs)[(size_t)(k - 1) * NSEQ + (128 * BS + b)];
            float4 vb = ((const float4*)zs)[(size_t)(k - 1) * NSEQ + (127 * BS + b)];
            za0 = va.x; za1 = va.y; za2 = va.z; za3 = va.w;
            zb0 = vb.x; zb1 = vb.y; zb2 = vb.z; zb3 = vb.w;
            #pragma unroll 4
            for (int j = 0; j < WARM_IIR; ++j) {
                float x = xg[j];
                (void)iir_step(qa, x, za0, za1, za2, za3);
                (void)iir_step(qb, x, zb0, zb1, zb2, zb3);
            }
            #pragma unroll 4
            for (int j = WARM_IIR; j < LFRM; ++j) {
                float x = xg[j];
                float ya = iir_step(qa, x, za0, za1, za2, za3);
                float yb = iir_step(qb, x, zb0, zb1, zb2, zb3);
                ua = fmaf(beta, ua, sigmoidf(ya));
                ub = fmaf(beta, ub, sigmoidf(yb));
            }
            off = LFRM;
        }
        float g = 0.f, yfirst = 0.f;
        #pragma unroll 4
        for (int j = 0; j < LFRM; ++j) {
            float x = xg[off + j];
            float ya = iir_step(qa, x, za0, za1, za2, za3);
            float yb = iir_step(qb, x, zb0, zb1, zb2, zb3);
            ua = fmaf(beta, ua, sigmoidf(ya));
            ub = fmaf(beta, ub, sigmoidf(yb));
            float y4 = fmaxf(ua - ub, 0.0f);
            if (j == 0) yfirst = y4;
            g = fmaf(alpha, g, y4);
        }
        size_t idx = (size_t)item * NCH + 128;
        G[idx] = g;
        y4f[idx] = yfirst;
        return;
    }

    // ---- main: one wave, lane t -> chains 2t, 2t+1; outputs 2t+1, 2t+2 ----
    int mblk = blk - CLEAN_BLOCKS;           // b * NFRM + k
    int b = mblk / NFRM;
    int k = mblk - b * NFRM;
    int kload = (k > 0) ? (k - 1) : 0;
    int nload = (k > 0) ? 2 * LFRM : LFRM;
    const float* xg = wav + (size_t)b * TLEN + (size_t)kload * LFRM;
    for (int i = threadIdx.x; i < nload; i += 64) xs[i] = xg[i];
    __syncthreads();

    int t = threadIdx.x;                     // 0..63
    int cA = 2 * t, cB = 2 * t + 1;          // chains (cB <= 127)
    Coef qa = load_coef(B, A, cA);
    Coef qb = load_coef(B, A, cB);
    float za0 = 0.f, za1 = 0.f, za2 = 0.f, za3 = 0.f;
    float zb0 = 0.f, zb1 = 0.f, zb2 = 0.f, zb3 = 0.f;
    float ua = 0.f, ub = 0.f;
    int off = 0;
    if (k > 0) {
        float4 va = ((const float4*)zs)[(size_t)(k - 1) * NSEQ + (cA * BS + b)];
        float4 vb = ((const float4*)zs)[(size_t)(k - 1) * NSEQ + (cB * BS + b)];
        za0 = va.x; za1 = va.y; za2 = va.z; za3 = va.w;
        zb0 = vb.x; zb1 = vb.y; zb2 = vb.z; zb3 = vb.w;
        #pragma unroll 4
        for (int j = 0; j < WARM_IIR; ++j) {
            float x = xs[j];
            (void)iir_step(qa, x, za0, za1, za2, za3);
            (void)iir_step(qb, x, zb0, zb1, zb2, zb3);
        }
        #pragma unroll 4
        for (int j = WARM_IIR; j < LFRM; ++j) {
            float x = xs[j];
            float ya = iir_step(qa, x, za0, za1, za2, za3);
            float yb = iir_step(qb, x, zb0, zb1, zb2, zb3);
            ua = fmaf(beta, ua, sigmoidf(ya));
            ub = fmaf(beta, ub, sigmoidf(yb));
        }
        off = LFRM;
    }
    float go, ge, fo, fe;
    {   // peel j = 0 (capture y4[t0] without a per-iter select)
        float x = xs[off];
        float ya = iir_step(qa, x, za0, za1, za2, za3);
        float yb = iir_step(qb, x, zb0, zb1, zb2, zb3);
        ua = fmaf(beta, ua, sigmoidf(ya));
        ub = fmaf(beta, ub, sigmoidf(yb));
        float un = __shfl_down(ua, 1, 64);   // chain 2t+2's u
        fo = go = fmaxf(ub - ua, 0.0f);      // channel 2t+1
        fe = ge = fmaxf(un - ub, 0.0f);      // channel 2t+2
    }
    #pragma unroll 4
    for (int j = 1; j < LFRM; ++j) {
        float x = xs[off + j];
        float ya = iir_step(qa, x, za0, za1, za2, za3);
        float yb = iir_step(qb, x, zb0, zb1, zb2, zb3);
        ua = fmaf(beta, ua, sigmoidf(ya));
        ub = fmaf(beta, ub, sigmoidf(yb));
        float un = __shfl_down(ua, 1, 64);
        float y4o = fmaxf(ub - ua, 0.0f);
        float y4e = fmaxf(un - ub, 0.0f);
        go = fmaf(alpha, go, y4o);
        ge = fmaf(alpha, ge, y4e);
    }
    size_t base = (size_t)mblk * NCH;
    G[base + cB] = go;            // channel 2t+1
    y4f[base + cB] = fo;
    if (t < 63) {
        G[base + cB + 1] = ge;    // channel 2t+2
        y4f[base + cB + 1] = fe;
    }
}

// ---------------------------------------------------------------------------
// Kernel D: per (b,c) exclusive alpha-scan over chunks.
//   y5[256k] = alpha * s_in[k] + y4[256k];  s_in[k+1] = alpha^L s_in[k] + G[k].
// Thread id = b*NCH + c so G/y4f reads are coalesced (c-major layout).
// ---------------------------------------------------------------------------
__global__ __launch_bounds__(64) void kD_alpha_scan(
        const float* __restrict__ G, const float* __restrict__ y4f,
        float* __restrict__ out, float alpha, float alphaL) {
    int id = blockIdx.x * 64 + threadIdx.x;   // b * NCH + c
    if (id >= NSEQ) return;
    int b = id / NCH;
    int c = id - b * NCH;
    float* o = out + (size_t)id * NFRM;       // (BS, NCH, NFRM) row
    if (c == 0) {
        for (int k = 0; k < NFRM; ++k) o[k] = 0.0f;
        return;
    }
    float s = 0.f;
    for (int k = 0; k < NFRM; k += 5) {       // 250 = 5*50
        float gk[5], yk[5];
        #pragma unroll
        for (int u = 0; u < 5; ++u) {
            size_t idx = ((size_t)b * NFRM + (k + u)) * NCH + c;
            gk[u] = G[idx];
            yk[u] = y4f[idx];
        }
        #pragma unroll
        for (int u = 0; u < 5; ++u) {
            o[k + u] = fmaf(alpha, s, yk[u]);
            s = fmaf(alphaL, s, gk[u]);
        }
    }
}

// ---------------------------------------------------------------------------
extern "C" void kernel_launch(void* const* d_in, const int* in_sizes, int n_in,
                              void* d_out, int out_size, void* d_ws, size_t ws_size,
                              hipStream_t stream) {
    const float* wav = (const float*)d_in[0];   // (BS, TLEN)
    const float* Bc  = (const float*)d_in[1];   // (NCH, 5)
    const float* Ac  = (const float*)d_in[2];   // (NCH, 5)
    float* out = (float*)d_out;                 // (BS, NCH, NFRM)

    // workspace: zs (NFRM*NSEQ float4) | G (NBK*NCH) | y4f (NBK*NCH)
    float* zs  = (float*)d_ws;
    float* G   = zs + (size_t)NFRM * NSEQ * 4;
    float* y4f = G + (size_t)NBK * NCH;

    const float alpha  = (float)exp(-1.0 / 128.0);
    const float beta   = (float)exp(-1.0 / 8.0);
    const float alphaL = (float)exp(-256.0 / 128.0);

    kA_forced_state<<<NBK, 192, 0, stream>>>(wav, Bc, Ac, zs);
    kB_state_scan<<<(NSEQ + 63) / 64, 64, 0, stream>>>(Ac, zs);
    kC_main<<<CLEAN_BLOCKS + NBK, 64, 0, stream>>>(wav, Bc, Ac, zs, G, y4f, beta, alpha);
    kD_alpha_scan<<<(NSEQ + 63) / 64, 64, 0, stream>>>(G, y4f, out, alpha, alphaL);
}

// Round 3
// 251.939 us; speedup vs baseline: 1.8049x; 1.8049x over previous
//
#include <hip/hip_runtime.h>
#include <math.h>

// Problem constants (from reference)
#define NCH 129
#define BS 8
#define TLEN 64000
#define LFRM 256          // frame stride == chunk length
#define NFRM 250          // number of frames / chunks
#define NSEQ (NCH * BS)   // 1032 sequences
#define NBK (BS * NFRM)   // 2000 (b,k) tiles

// Warm-up split: first WARM_IIR steps of the previous chunk evolve the IIR
// state only; sigmoid+beta accumulate over the last LFRM-WARM_IIR steps.
// beta^128 = e^-16 -> truncation err ~1e-7 absolute, amplified <=128x by the
// alpha-sum -> ~1e-5. Negligible vs the ~9.88 absmax threshold.
#define WARM_IIR 128

struct Coef { float b0, b1, b2, b3, b4, a1, a2, a3, a4; };

__device__ __forceinline__ Coef load_coef(const float* __restrict__ B,
                                          const float* __restrict__ A, int c) {
    Coef q;
    q.b0 = B[c * 5 + 0]; q.b1 = B[c * 5 + 1]; q.b2 = B[c * 5 + 2];
    q.b3 = B[c * 5 + 3]; q.b4 = B[c * 5 + 4];
    q.a1 = A[c * 5 + 1]; q.a2 = A[c * 5 + 2];
    q.a3 = A[c * 5 + 3]; q.a4 = A[c * 5 + 4];
    return q;
}

// Direct-form II transposed, order 4.
__device__ __forceinline__ float iir_step(const Coef& q, float x,
                                          float& z0, float& z1, float& z2, float& z3) {
    float y = fmaf(q.b0, x, z0);
    z0 = fmaf(-q.a1, y, fmaf(q.b1, x, z1));
    z1 = fmaf(-q.a2, y, fmaf(q.b2, x, z2));
    z2 = fmaf(-q.a3, y, fmaf(q.b3, x, z3));
    z3 = fmaf(-q.a4, y, q.b4 * x);
    return y;
}

// rcp-based sigmoid: 2 transcendental + 2 simple ops (vs IEEE divide seq).
__device__ __forceinline__ float sigmoidf(float x) {
    return __builtin_amdgcn_rcpf(1.0f + __expf(-x));
}

// ---------------------------------------------------------------------------
// Kernel A: per (c, b, chunk) zero-state order-4 IIR over the chunk -> final
// 4-state (forced response). zs layout: float4 at [k * NSEQ + (c*BS+b)].
// ---------------------------------------------------------------------------
__global__ __launch_bounds__(192) void kA_forced_state(
        const float* __restrict__ wav, const float* __restrict__ B,
        const float* __restrict__ A, float* __restrict__ zs) {
    __shared__ float xs[LFRM];
    int blk = blockIdx.x;            // b * NFRM + k
    int b = blk / NFRM;
    int k = blk - b * NFRM;
    const float* xg = wav + (size_t)b * TLEN + (size_t)k * LFRM;
    for (int i = threadIdx.x; i < LFRM; i += 192) xs[i] = xg[i];
    __syncthreads();
    int c = threadIdx.x;
    if (c >= NCH) return;
    Coef q = load_coef(B, A, c);
    float z0 = 0.f, z1 = 0.f, z2 = 0.f, z3 = 0.f;
    #pragma unroll 8
    for (int j = 0; j < LFRM; ++j) {
        (void)iir_step(q, xs[j], z0, z1, z2, z3);
    }
    ((float4*)zs)[(size_t)k * NSEQ + (c * BS + b)] = make_float4(z0, z1, z2, z3);
}

// ---------------------------------------------------------------------------
// Kernel B: per (c,b) sequence — M^256 by repeated squaring, then scan:
//   z_in[k] = M^L * z_in[k-1] + d[k-1],  z_in[0] = 0  (in place, k-major ->
// coalesced float4 loads across the 1032 lanes).
// ---------------------------------------------------------------------------
__global__ __launch_bounds__(64) void kB_state_scan(
        const float* __restrict__ A, float* __restrict__ zs) {
    int id = blockIdx.x * 64 + threadIdx.x;   // c * BS + b
    if (id >= NSEQ) return;
    int c = id / BS;
    float a1 = A[c * 5 + 1], a2 = A[c * 5 + 2], a3 = A[c * 5 + 3], a4 = A[c * 5 + 4];
    float M[4][4] = {{-a1, 1.f, 0.f, 0.f},
                     {-a2, 0.f, 1.f, 0.f},
                     {-a3, 0.f, 0.f, 1.f},
                     {-a4, 0.f, 0.f, 0.f}};
    for (int s = 0; s < 8; ++s) {        // M^(2^8) = M^256
        float R[4][4];
        for (int i = 0; i < 4; ++i)
            for (int j = 0; j < 4; ++j) {
                float acc = 0.f;
                for (int t = 0; t < 4; ++t) acc = fmaf(M[i][t], M[t][j], acc);
                R[i][j] = acc;
            }
        for (int i = 0; i < 4; ++i)
            for (int j = 0; j < 4; ++j) M[i][j] = R[i][j];
    }
    float4* zb = (float4*)zs;
    float s0 = 0.f, s1 = 0.f, s2 = 0.f, s3 = 0.f;
    for (int k = 0; k < NFRM; k += 5) {            // 250 = 5*50
        float4 d[5];
        #pragma unroll
        for (int u = 0; u < 5; ++u) d[u] = zb[(size_t)(k + u) * NSEQ + id];
        #pragma unroll
        for (int u = 0; u < 5; ++u) {
            zb[(size_t)(k + u) * NSEQ + id] = make_float4(s0, s1, s2, s3);
            float n0 = fmaf(M[0][0], s0, fmaf(M[0][1], s1, fmaf(M[0][2], s2, fmaf(M[0][3], s3, d[u].x))));
            float n1 = fmaf(M[1][0], s0, fmaf(M[1][1], s1, fmaf(M[1][2], s2, fmaf(M[1][3], s3, d[u].y))));
            float n2 = fmaf(M[2][0], s0, fmaf(M[2][1], s1, fmaf(M[2][2], s2, fmaf(M[2][3], s3, d[u].z))));
            float n3 = fmaf(M[3][0], s0, fmaf(M[3][1], s1, fmaf(M[3][2], s2, fmaf(M[3][3], s3, d[u].w))));
            s0 = n0; s1 = n1; s2 = n2; s3 = n3;
        }
    }
}

// ---------------------------------------------------------------------------
// Kernel C-edge: channel-128 output terms. One thread per (b,k) tile running
// chains 127 & 128 (round-1-proven code shape). Only 32 waves — latency-bound
// but small; x reads are uncoalesced (per-lane chunk base) and served by L2.
// ---------------------------------------------------------------------------
__global__ __launch_bounds__(64, 4) void kC_edge(
        const float* __restrict__ wav, const float* __restrict__ B,
        const float* __restrict__ A, const float* __restrict__ zs,
        float* __restrict__ G, float* __restrict__ y4f,
        float beta, float alpha) {
    int item = blockIdx.x * 64 + threadIdx.x;   // b * NFRM + k
    if (item >= NBK) return;
    int b = item / NFRM;
    int k = item - b * NFRM;
    int kload = (k > 0) ? (k - 1) : 0;
    const float* xg = wav + (size_t)b * TLEN + (size_t)kload * LFRM;
    Coef qa = load_coef(B, A, 128);
    Coef qb = load_coef(B, A, 127);
    float za0 = 0.f, za1 = 0.f, za2 = 0.f, za3 = 0.f;
    float zb0 = 0.f, zb1 = 0.f, zb2 = 0.f, zb3 = 0.f;
    float ua = 0.f, ub = 0.f;
    int off = 0;
    if (k > 0) {
        float4 va = ((const float4*)zs)[(size_t)(k - 1) * NSEQ + (128 * BS + b)];
        float4 vb = ((const float4*)zs)[(size_t)(k - 1) * NSEQ + (127 * BS + b)];
        za0 = va.x; za1 = va.y; za2 = va.z; za3 = va.w;
        zb0 = vb.x; zb1 = vb.y; zb2 = vb.z; zb3 = vb.w;
        #pragma unroll 2
        for (int j = 0; j < WARM_IIR; ++j) {
            float x = xg[j];
            (void)iir_step(qa, x, za0, za1, za2, za3);
            (void)iir_step(qb, x, zb0, zb1, zb2, zb3);
        }
        #pragma unroll 2
        for (int j = WARM_IIR; j < LFRM; ++j) {
            float x = xg[j];
            float ya = iir_step(qa, x, za0, za1, za2, za3);
            float yb = iir_step(qb, x, zb0, zb1, zb2, zb3);
            ua = fmaf(beta, ua, sigmoidf(ya));
            ub = fmaf(beta, ub, sigmoidf(yb));
        }
        off = LFRM;
    }
    float g = 0.f, yfirst = 0.f;
    #pragma unroll 2
    for (int j = 0; j < LFRM; ++j) {
        float x = xg[off + j];
        float ya = iir_step(qa, x, za0, za1, za2, za3);
        float yb = iir_step(qb, x, zb0, zb1, zb2, zb3);
        ua = fmaf(beta, ua, sigmoidf(ya));
        ub = fmaf(beta, ub, sigmoidf(yb));
        float y4 = fmaxf(ua - ub, 0.0f);
        if (j == 0) yfirst = y4;
        g = fmaf(alpha, g, y4);
    }
    size_t idx = (size_t)item * NCH + 128;
    G[idx] = g;
    y4f[idx] = yfirst;
}

// ---------------------------------------------------------------------------
// Kernel C-main: pair-channel. One wave per (b,k) tile; lane t runs chains
// 2t & 2t+1 from exact z_in[k-1] (warm-up over chunk k-1 for the beta state),
// emits y4-terms for channels 2t+1 (local) and 2t+2 (ua from lane t+1 via
// shfl_down). Covers channels 1..127; 128 comes from kC_edge; 0 is zero (kD).
// G/y4f layout: [(b*NFRM+k)*NCH + c].
// ---------------------------------------------------------------------------
__global__ __launch_bounds__(64, 4) void kC_main(
        const float* __restrict__ wav, const float* __restrict__ B,
        const float* __restrict__ A, const float* __restrict__ zs,
        float* __restrict__ G, float* __restrict__ y4f,
        float beta, float alpha) {
    __shared__ float xs[2 * LFRM];
    int blk = blockIdx.x;            // b * NFRM + k
    int b = blk / NFRM;
    int k = blk - b * NFRM;
    int kload = (k > 0) ? (k - 1) : 0;
    int nload = (k > 0) ? 2 * LFRM : LFRM;
    const float* xg = wav + (size_t)b * TLEN + (size_t)kload * LFRM;
    for (int i = threadIdx.x; i < nload; i += 64) xs[i] = xg[i];
    __syncthreads();

    int t = threadIdx.x;                     // 0..63
    int cA = 2 * t, cB = 2 * t + 1;          // chains (cB <= 127)
    Coef qa = load_coef(B, A, cA);
    Coef qb = load_coef(B, A, cB);
    float za0 = 0.f, za1 = 0.f, za2 = 0.f, za3 = 0.f;
    float zb0 = 0.f, zb1 = 0.f, zb2 = 0.f, zb3 = 0.f;
    float ua = 0.f, ub = 0.f;
    int off = 0;
    if (k > 0) {
        float4 va = ((const float4*)zs)[(size_t)(k - 1) * NSEQ + (cA * BS + b)];
        float4 vb = ((const float4*)zs)[(size_t)(k - 1) * NSEQ + (cB * BS + b)];
        za0 = va.x; za1 = va.y; za2 = va.z; za3 = va.w;
        zb0 = vb.x; zb1 = vb.y; zb2 = vb.z; zb3 = vb.w;
        #pragma unroll 2
        for (int j = 0; j < WARM_IIR; ++j) {
            float x = xs[j];
            (void)iir_step(qa, x, za0, za1, za2, za3);
            (void)iir_step(qb, x, zb0, zb1, zb2, zb3);
        }
        #pragma unroll 2
        for (int j = WARM_IIR; j < LFRM; ++j) {
            float x = xs[j];
            float ya = iir_step(qa, x, za0, za1, za2, za3);
            float yb = iir_step(qb, x, zb0, zb1, zb2, zb3);
            ua = fmaf(beta, ua, sigmoidf(ya));
            ub = fmaf(beta, ub, sigmoidf(yb));
        }
        off = LFRM;
    }
    float go = 0.f, ge = 0.f, fo = 0.f, fe = 0.f;
    #pragma unroll 2
    for (int j = 0; j < LFRM; ++j) {
        float x = xs[off + j];
        float ya = iir_step(qa, x, za0, za1, za2, za3);
        float yb = iir_step(qb, x, zb0, zb1, zb2, zb3);
        ua = fmaf(beta, ua, sigmoidf(ya));
        ub = fmaf(beta, ub, sigmoidf(yb));
        float un = __shfl_down(ua, 1, 64);   // chain 2t+2's u (lane t+1)
        float y4o = fmaxf(ub - ua, 0.0f);    // channel 2t+1
        float y4e = fmaxf(un - ub, 0.0f);    // channel 2t+2
        if (j == 0) { fo = y4o; fe = y4e; }
        go = fmaf(alpha, go, y4o);
        ge = fmaf(alpha, ge, y4e);
    }
    size_t base = (size_t)blk * NCH;
    G[base + cB] = go;            // channel 2t+1 (odd 1..127)
    y4f[base + cB] = fo;
    if (t < 63) {
        G[base + cB + 1] = ge;    // channel 2t+2 (even 2..126)
        y4f[base + cB + 1] = fe;
    }
}

// ---------------------------------------------------------------------------
// Kernel D: per (b,c) exclusive alpha-scan over chunks.
//   y5[256k] = alpha * s_in[k] + y4[256k];  s_in[k+1] = alpha^L s_in[k] + G[k].
// ---------------------------------------------------------------------------
__global__ __launch_bounds__(64) void kD_alpha_scan(
        const float* __restrict__ G, const float* __restrict__ y4f,
        float* __restrict__ out, float alpha, float alphaL) {
    int id = blockIdx.x * 64 + threadIdx.x;   // b * NCH + c
    if (id >= NSEQ) return;
    int b = id / NCH;
    int c = id - b * NCH;
    float* o = out + (size_t)id * NFRM;       // (BS, NCH, NFRM) row
    if (c == 0) {
        for (int k = 0; k < NFRM; ++k) o[k] = 0.0f;
        return;
    }
    float s = 0.f;
    for (int k = 0; k < NFRM; k += 5) {       // 250 = 5*50
        float gk[5], yk[5];
        #pragma unroll
        for (int u = 0; u < 5; ++u) {
            size_t idx = ((size_t)b * NFRM + (k + u)) * NCH + c;
            gk[u] = G[idx];
            yk[u] = y4f[idx];
        }
        #pragma unroll
        for (int u = 0; u < 5; ++u) {
            o[k + u] = fmaf(alpha, s, yk[u]);
            s = fmaf(alphaL, s, gk[u]);
        }
    }
}

// ---------------------------------------------------------------------------
extern "C" void kernel_launch(void* const* d_in, const int* in_sizes, int n_in,
                              void* d_out, int out_size, void* d_ws, size_t ws_size,
                              hipStream_t stream) {
    const float* wav = (const float*)d_in[0];   // (BS, TLEN)
    const float* Bc  = (const float*)d_in[1];   // (NCH, 5)
    const float* Ac  = (const float*)d_in[2];   // (NCH, 5)
    float* out = (float*)d_out;                 // (BS, NCH, NFRM)

    // workspace: zs (NFRM*NSEQ float4) | G (NBK*NCH) | y4f (NBK*NCH)
    float* zs  = (float*)d_ws;
    float* G   = zs + (size_t)NFRM * NSEQ * 4;
    float* y4f = G + (size_t)NBK * NCH;

    const float alpha  = (float)exp(-1.0 / 128.0);
    const float beta   = (float)exp(-1.0 / 8.0);
    const float alphaL = (float)exp(-256.0 / 128.0);

    kA_forced_state<<<NBK, 192, 0, stream>>>(wav, Bc, Ac, zs);
    kB_state_scan<<<(NSEQ + 63) / 64, 64, 0, stream>>>(Ac, zs);
    kC_edge<<<(NBK + 63) / 64, 64, 0, stream>>>(wav, Bc, Ac, zs, G, y4f, beta, alpha);
    kC_main<<<NBK, 64, 0, stream>>>(wav, Bc, Ac, zs, G, y4f, beta, alpha);
    kD_alpha_scan<<<(NSEQ + 63) / 64, 64, 0, stream>>>(G, y4f, out, alpha, alphaL);
}